// Round 3
// baseline (598.163 us; speedup 1.0000x reference)
//
#include <hip/hip_runtime.h>
#include <hip/hip_bf16.h>
#include <cstdint>

#define BB 4
#define TT 2048
#define CC 1024
#define HH 16
#define HS 64
#define MM (BB*TT)   // 8192

typedef _Float16 f16;
typedef _Float16 f16x8 __attribute__((ext_vector_type(8)));
typedef _Float16 f16x4 __attribute__((ext_vector_type(4)));
typedef float f32x4 __attribute__((ext_vector_type(4)));

#define MFMA16(a,b,c) __builtin_amdgcn_mfma_f32_16x16x32_f16(a,b,c,0,0,0)

__device__ __forceinline__ void g2lds16(void* lds, const void* g) {
  __builtin_amdgcn_global_load_lds(
      (const __attribute__((address_space(1))) void*)g,
      (__attribute__((address_space(3))) void*)lds, 16, 0, 0);
}

// ---------------- pre-pass: f32 -> f16 convert ----------------
__global__ __launch_bounds__(256) void cvt_kernel(const float* __restrict__ in,
                                                  f16* __restrict__ out, int n4) {
  int i = blockIdx.x * blockDim.x + threadIdx.x;
  if (i < n4) {
    float4 v = ((const float4*)in)[i];
    f16x4 o;
    o[0] = (f16)v.x; o[1] = (f16)v.y; o[2] = (f16)v.z; o[3] = (f16)v.w;
    ((f16x4*)out)[i] = o;
  }
}

// ---------------- pre-pass: transpose + convert: in[K][N] f32 -> out[N][K] f16
__global__ __launch_bounds__(256) void transpose_cvt(const float* __restrict__ in,
                                                     f16* __restrict__ out,
                                                     int K, int N) {
  __shared__ float tile[32][33];
  int n0 = blockIdx.x * 32, k0 = blockIdx.y * 32;
  int tx = threadIdx.x, ty = threadIdx.y;
  #pragma unroll
  for (int i = 0; i < 32; i += 8)
    tile[ty + i][tx] = in[(size_t)(k0 + ty + i) * N + n0 + tx];
  __syncthreads();
  #pragma unroll
  for (int i = 0; i < 32; i += 8)
    out[(size_t)(n0 + ty + i) * K + k0 + tx] = (f16)tile[tx][ty + i];
}

// ---------------- GEMM: C[M][N] = A[M][1024] * Bt[N][1024]^T ----------------
// EPI 0: scatter to qT/kT (row-major [B,H,T,64]) and vT (transposed [B,H,64,T])
// EPI 1: f32 out + bias
template<int EPI>
__global__ __launch_bounds__(256) void gemm_bt(const f16* __restrict__ A,
                                               const f16* __restrict__ Bt,
                                               f16* __restrict__ qT,
                                               f16* __restrict__ kT,
                                               f16* __restrict__ vT,
                                               const float* __restrict__ bias,
                                               float* __restrict__ outF) {
  const int K = 1024;
  __shared__ f16 As[128 * 64];
  __shared__ f16 Bs[128 * 64];
  const int t = threadIdx.x;
  const int l = t & 63, w = t >> 6;
  const int lr = l & 15, lh = l >> 4;
  const int row0 = blockIdx.y * 128, col0 = blockIdx.x * 128;
  const int wr = (w >> 1) * 64, wc = (w & 1) * 64;

  f32x4 acc[4][4] = {};

  for (int kt = 0; kt < K; kt += 64) {
    #pragma unroll
    for (int issue = 0; issue < 4; ++issue) {
      int r  = issue * 32 + w * 8 + (l >> 3);
      int cb = (l & 7) * 8;  // element offset within 64-wide k tile
      g2lds16(&As[r * 64 + cb], &A [(size_t)(row0 + r) * K + kt + cb]);
      g2lds16(&Bs[r * 64 + cb], &Bt[(size_t)(col0 + r) * K + kt + cb]);
    }
    __syncthreads();
    #pragma unroll
    for (int kk = 0; kk < 64; kk += 32) {
      f16x8 af[4], bfr[4];
      #pragma unroll
      for (int m = 0; m < 4; ++m)
        af[m]  = *(const f16x8*)&As[(wr + m * 16 + lr) * 64 + kk + lh * 8];
      #pragma unroll
      for (int n = 0; n < 4; ++n)
        bfr[n] = *(const f16x8*)&Bs[(wc + n * 16 + lr) * 64 + kk + lh * 8];
      #pragma unroll
      for (int m = 0; m < 4; ++m)
        #pragma unroll
        for (int n = 0; n < 4; ++n)
          acc[m][n] = MFMA16(af[m], bfr[n], acc[m][n]);
    }
    __syncthreads();
  }

  #pragma unroll
  for (int m = 0; m < 4; ++m) {
    #pragma unroll
    for (int n = 0; n < 4; ++n) {
      #pragma unroll
      for (int j = 0; j < 4; ++j) {
        float val = acc[m][n][j];
        int gr = row0 + wr + m * 16 + lh * 4 + j;   // M index
        int gc = col0 + wc + n * 16 + lr;           // N index
        if (EPI == 0) {
          int which = gc >> 10;          // 0=q 1=k 2=v
          int c = gc & 1023;
          int h = c >> 6, d = c & 63;
          int b = gr >> 11, tt = gr & 2047;
          size_t bh = (size_t)(b * HH + h);
          if (which == 0)      qT[(bh * TT + tt) * HS + d] = (f16)val;
          else if (which == 1) kT[(bh * TT + tt) * HS + d] = (f16)val;
          else                 vT[(bh * HS + d) * TT + tt] = (f16)val;
        } else {
          outF[(size_t)gr * CC + gc] = val + bias[gc];
        }
      }
    }
  }
}

// ---------------- flash attention ----------------
// grid: (32 q-tiles, 64 b*h). block 256 = 4 waves, each wave owns 16 q rows.
// scale is *sqrt(HS) = 8 (faithful to reference).
__global__ __launch_bounds__(256) void attn_kernel(const f16* __restrict__ qT,
                                                   const f16* __restrict__ kT,
                                                   const f16* __restrict__ vT,
                                                   f16* __restrict__ aout) {
  const int qt = blockIdx.x;
  const int bh = blockIdx.y;
  const int t = threadIdx.x, l = t & 63, w = t >> 6;
  const int lr = l & 15, lh = l >> 4;
  const int q0 = qt * 64 + w * 16;
  const f16* Qb = qT + (size_t)bh * TT * HS;
  const f16* Kb = kT + (size_t)bh * TT * HS;
  const f16* Vb = vT + (size_t)bh * HS * TT;
  __shared__ f16 P_lds[4][16][32];

  f16x8 qf0 = *(const f16x8*)&Qb[(q0 + lr) * HS + lh * 8];
  f16x8 qf1 = *(const f16x8*)&Qb[(q0 + lr) * HS + 32 + lh * 8];

  float mrow[4] = {-INFINITY, -INFINITY, -INFINITY, -INFINITY};
  float lrow[4] = {0.f, 0.f, 0.f, 0.f};
  f32x4 o[4] = {};

  const int kend = qt * 64 + 64;  // uniform trip count across block (barrier-safe)
  for (int kb = 0; kb < kend; kb += 32) {
    f32x4 s0 = {}, s1 = {};
    {
      f16x8 kf0 = *(const f16x8*)&Kb[(kb + lr) * HS + lh * 8];
      f16x8 kf1 = *(const f16x8*)&Kb[(kb + lr) * HS + 32 + lh * 8];
      s0 = MFMA16(qf0, kf0, s0);
      s0 = MFMA16(qf1, kf1, s0);
      f16x8 kf2 = *(const f16x8*)&Kb[(kb + 16 + lr) * HS + lh * 8];
      f16x8 kf3 = *(const f16x8*)&Kb[(kb + 16 + lr) * HS + 32 + lh * 8];
      s1 = MFMA16(qf0, kf2, s1);
      s1 = MFMA16(qf1, kf3, s1);
    }
    #pragma unroll
    for (int r = 0; r < 4; ++r) {
      int q = q0 + lh * 4 + r;
      s0[r] = (kb + lr)      <= q ? s0[r] * 8.0f : -INFINITY;
      s1[r] = (kb + 16 + lr) <= q ? s1[r] * 8.0f : -INFINITY;
    }
    #pragma unroll
    for (int r = 0; r < 4; ++r) {
      float mx = fmaxf(s0[r], s1[r]);
      mx = fmaxf(mx, __shfl_xor(mx, 1));
      mx = fmaxf(mx, __shfl_xor(mx, 2));
      mx = fmaxf(mx, __shfl_xor(mx, 4));
      mx = fmaxf(mx, __shfl_xor(mx, 8));
      float mn = fmaxf(mrow[r], mx);
      float corr = __expf(mrow[r] - mn);
      mrow[r] = mn;
      float p0 = __expf(s0[r] - mn);
      float p1 = __expf(s1[r] - mn);
      float ps = p0 + p1;
      ps += __shfl_xor(ps, 1);
      ps += __shfl_xor(ps, 2);
      ps += __shfl_xor(ps, 4);
      ps += __shfl_xor(ps, 8);
      lrow[r] = lrow[r] * corr + ps;
      #pragma unroll
      for (int dg = 0; dg < 4; ++dg) o[dg][r] *= corr;
      P_lds[w][lh * 4 + r][lr]      = (f16)p0;
      P_lds[w][lh * 4 + r][16 + lr] = (f16)p1;
    }
    __syncthreads();
    f16x8 pf = *(const f16x8*)&P_lds[w][lr][lh * 8];
    #pragma unroll
    for (int dg = 0; dg < 4; ++dg) {
      f16x8 vf = *(const f16x8*)&Vb[(dg * 16 + lr) * TT + kb + lh * 8];
      o[dg] = MFMA16(pf, vf, o[dg]);
    }
    __syncthreads();
  }

  const int b = bh >> 4, h = bh & 15;
  float inv[4];
  #pragma unroll
  for (int r = 0; r < 4; ++r) inv[r] = 1.0f / lrow[r];
  #pragma unroll
  for (int dg = 0; dg < 4; ++dg) {
    #pragma unroll
    for (int r = 0; r < 4; ++r) {
      int q = q0 + lh * 4 + r;
      float val = o[dg][r] * inv[r];
      aout[((size_t)(b * TT + q)) * CC + h * HS + dg * 16 + lr] = (f16)val;
    }
  }
}

// ---------------- launch ----------------
extern "C" void kernel_launch(void* const* d_in, const int* in_sizes, int n_in,
                              void* d_out, int out_size, void* d_ws, size_t ws_size,
                              hipStream_t stream) {
  const float* x      = (const float*)d_in[0];
  const float* w_kqv  = (const float*)d_in[1];
  const float* w_proj = (const float*)d_in[2];
  const float* b_proj = (const float*)d_in[3];
  float* out = (float*)d_out;

  char* ws = (char*)d_ws;
  f16* xb    = (f16*)(ws);                       // 8192*1024*2   = 16,777,216
  f16* wkqvT = (f16*)(ws + 16777216);            // 3072*1024*2   =  6,291,456
  f16* wpT   = (f16*)(ws + 23068672);            // 1024*1024*2   =  2,097,152
  f16* qT    = (f16*)(ws + 25165824);            // 16,777,216
  f16* kT    = (f16*)(ws + 41943040);            // 16,777,216
  f16* vT    = (f16*)(ws + 58720256);            // 16,777,216
  f16* aout  = (f16*)(ws + 75497472);            // 16,777,216  -> total ~92.3 MB

  // pre-pass
  cvt_kernel<<<8192, 256, 0, stream>>>(x, xb, (MM * CC) / 4);
  transpose_cvt<<<dim3(3 * CC / 32, CC / 32), dim3(32, 8), 0, stream>>>(w_kqv, wkqvT, CC, 3 * CC);
  transpose_cvt<<<dim3(CC / 32, CC / 32), dim3(32, 8), 0, stream>>>(w_proj, wpT, CC, CC);

  // qkv = x @ w_kqv  (M=8192, N=3072), scatter into qT/kT/vT
  gemm_bt<0><<<dim3(3 * CC / 128, MM / 128), 256, 0, stream>>>(xb, wkqvT, qT, kT, vT, nullptr, nullptr);

  // attention
  attn_kernel<<<dim3(TT / 64, BB * HH), 256, 0, stream>>>(qT, kT, vT, aout);

  // out = attn @ w_proj + b_proj  (M=8192, N=1024), f32 out
  gemm_bt<1><<<dim3(CC / 128, MM / 128), 256, 0, stream>>>(aout, wpT, nullptr, nullptr, nullptr, b_proj, out);
}

// Round 5
// 380.649 us; speedup vs baseline: 1.5714x; 1.5714x over previous
//
#include <hip/hip_runtime.h>
#include <hip/hip_bf16.h>
#include <cstdint>

#define BB 4
#define TT 2048
#define CC 1024
#define HH 16
#define HS 64
#define MM (BB*TT)   // 8192

typedef _Float16 f16;
typedef _Float16 f16x8 __attribute__((ext_vector_type(8)));
typedef _Float16 f16x4 __attribute__((ext_vector_type(4)));
typedef float f32x4 __attribute__((ext_vector_type(4)));

#define MFMA16(a,b,c) __builtin_amdgcn_mfma_f32_16x16x32_f16(a,b,c,0,0,0)

__device__ __forceinline__ void g2lds16(void* lds, const void* g) {
  __builtin_amdgcn_global_load_lds(
      (const __attribute__((address_space(1))) void*)g,
      (__attribute__((address_space(3))) void*)lds, 16, 0, 0);
}

// ---------------- pre-pass: f32 -> f16 convert ----------------
__global__ __launch_bounds__(256) void cvt_kernel(const float* __restrict__ in,
                                                  f16* __restrict__ out, int n4) {
  int i = blockIdx.x * blockDim.x + threadIdx.x;
  if (i < n4) {
    float4 v = ((const float4*)in)[i];
    f16x4 o;
    o[0] = (f16)v.x; o[1] = (f16)v.y; o[2] = (f16)v.z; o[3] = (f16)v.w;
    ((f16x4*)out)[i] = o;
  }
}

// ---------------- pre-pass: transpose + convert: in[K][N] f32 -> out[N][K] f16
__global__ __launch_bounds__(256) void transpose_cvt(const float* __restrict__ in,
                                                     f16* __restrict__ out,
                                                     int K, int N) {
  __shared__ float tile[32][33];
  int n0 = blockIdx.x * 32, k0 = blockIdx.y * 32;
  int tx = threadIdx.x, ty = threadIdx.y;
  #pragma unroll
  for (int i = 0; i < 32; i += 8)
    tile[ty + i][tx] = in[(size_t)(k0 + ty + i) * N + n0 + tx];
  __syncthreads();
  #pragma unroll
  for (int i = 0; i < 32; i += 8)
    out[(size_t)(n0 + ty + i) * K + k0 + tx] = (f16)tile[tx][ty + i];
}

// ---------------- GEMM: C[M][N] = A[M][1024] * Bt[N][1024]^T ----------------
template<int EPI>
__global__ __launch_bounds__(256) void gemm_bt(const f16* __restrict__ A,
                                               const f16* __restrict__ Bt,
                                               f16* __restrict__ qT,
                                               f16* __restrict__ kT,
                                               f16* __restrict__ vT,
                                               const float* __restrict__ bias,
                                               float* __restrict__ outF) {
  const int K = 1024;
  __shared__ f16 As[128 * 64];
  __shared__ f16 Bs[128 * 64];
  const int t = threadIdx.x;
  const int l = t & 63, w = t >> 6;
  const int lr = l & 15, lh = l >> 4;
  const int row0 = blockIdx.y * 128, col0 = blockIdx.x * 128;
  const int wr = (w >> 1) * 64, wc = (w & 1) * 64;

  f32x4 acc[4][4] = {};

  for (int kt = 0; kt < K; kt += 64) {
    #pragma unroll
    for (int issue = 0; issue < 4; ++issue) {
      int r  = issue * 32 + w * 8 + (l >> 3);
      int cb = (l & 7) * 8;
      g2lds16(&As[r * 64 + cb], &A [(size_t)(row0 + r) * K + kt + cb]);
      g2lds16(&Bs[r * 64 + cb], &Bt[(size_t)(col0 + r) * K + kt + cb]);
    }
    __syncthreads();
    #pragma unroll
    for (int kk = 0; kk < 64; kk += 32) {
      f16x8 af[4], bfr[4];
      #pragma unroll
      for (int m = 0; m < 4; ++m)
        af[m]  = *(const f16x8*)&As[(wr + m * 16 + lr) * 64 + kk + lh * 8];
      #pragma unroll
      for (int n = 0; n < 4; ++n)
        bfr[n] = *(const f16x8*)&Bs[(wc + n * 16 + lr) * 64 + kk + lh * 8];
      #pragma unroll
      for (int m = 0; m < 4; ++m)
        #pragma unroll
        for (int n = 0; n < 4; ++n)
          acc[m][n] = MFMA16(af[m], bfr[n], acc[m][n]);
    }
    __syncthreads();
  }

  #pragma unroll
  for (int m = 0; m < 4; ++m) {
    #pragma unroll
    for (int n = 0; n < 4; ++n) {
      #pragma unroll
      for (int j = 0; j < 4; ++j) {
        float val = acc[m][n][j];
        int gr = row0 + wr + m * 16 + lh * 4 + j;   // M index
        int gc = col0 + wc + n * 16 + lr;           // N index
        if (EPI == 0) {
          int which = gc >> 10;          // 0=q 1=k 2=v
          int c = gc & 1023;
          int h = c >> 6, d = c & 63;
          int b = gr >> 11, tt = gr & 2047;
          size_t bh = (size_t)(b * HH + h);
          if (which == 0)      qT[(bh * TT + tt) * HS + d] = (f16)val;
          else if (which == 1) kT[(bh * TT + tt) * HS + d] = (f16)val;
          else                 vT[(bh * HS + d) * TT + tt] = (f16)val;
        } else {
          outF[(size_t)gr * CC + gc] = val + bias[gc];
        }
      }
    }
  }
}

// ---------------- flash attention (swapped-QK^T, balanced pair, barrier-free) --
// grid: (64 bh, 16 pairs). block 256 = 4 waves, each wave owns 16 q rows.
// Each block does q-tile qp and q-tile 31-qp -> uniform 33 iteration-units.
// Swapped MFMA(K,Q): S^T layout; each lane holds 8 scores for ONE q (q=q0+lr),
// so row-reduce = 7 in-lane ops + 2 shfls. scale *sqrt(HS)=8 (faithful).
__global__ __launch_bounds__(256) void attn_kernel(const f16* __restrict__ qT,
                                                   const f16* __restrict__ kT,
                                                   const f16* __restrict__ vT,
                                                   f16* __restrict__ aout) {
  const int bh = blockIdx.x;   // x-fastest dispatch -> all 16 blocks of one bh on XCD bh%8
  const int qp = blockIdx.y;
  const int t = threadIdx.x, l = t & 63, w = t >> 6;
  const int lr = l & 15, lh = l >> 4;
  const f16* Qb = qT + (size_t)bh * TT * HS;
  const f16* Kb = kT + (size_t)bh * TT * HS;
  const f16* Vb = vT + (size_t)bh * HS * TT;
  const int b = bh >> 4, h = bh & 15;
  __shared__ f16 P_lds[4][16][32];   // per-wave private: no barriers needed

  #pragma unroll
  for (int half = 0; half < 2; ++half) {
    const int tile = (half == 0) ? qp : 31 - qp;
    const int q0 = tile * 64 + w * 16;
    const int q = q0 + lr;                    // this lane's q row (softmax layout)
    f16x8 qf0 = *(const f16x8*)&Qb[(size_t)q * HS + lh * 8];
    f16x8 qf1 = *(const f16x8*)&Qb[(size_t)q * HS + 32 + lh * 8];

    float m = -INFINITY, lsum = 0.f;
    f32x4 o[4] = {};

    const int kend = (q0 + 16 + 31) & ~31;    // per-wave trip count (no barriers)
    for (int kb = 0; kb < kend; kb += 32) {
      f32x4 s0 = {}, s1 = {};
      {
        f16x8 kf0 = *(const f16x8*)&Kb[(size_t)(kb + lr) * HS + lh * 8];
        f16x8 kf1 = *(const f16x8*)&Kb[(size_t)(kb + lr) * HS + 32 + lh * 8];
        f16x8 kf2 = *(const f16x8*)&Kb[(size_t)(kb + 16 + lr) * HS + lh * 8];
        f16x8 kf3 = *(const f16x8*)&Kb[(size_t)(kb + 16 + lr) * HS + 32 + lh * 8];
        s0 = MFMA16(kf0, qf0, s0);   // S^T[k][q]
        s0 = MFMA16(kf1, qf1, s0);
        s1 = MFMA16(kf2, qf0, s1);
        s1 = MFMA16(kf3, qf1, s1);
      }
      const int k0 = kb + lh * 4;   // lane's k rows: k0+r (s0), k0+16+r (s1)
      float p[8];
      #pragma unroll
      for (int r = 0; r < 4; ++r) {
        p[r]     = (k0 + r      <= q) ? s0[r] * 8.0f : -INFINITY;
        p[4 + r] = (k0 + 16 + r <= q) ? s1[r] * 8.0f : -INFINITY;
      }
      float mx = p[0];
      #pragma unroll
      for (int i = 1; i < 8; ++i) mx = fmaxf(mx, p[i]);
      mx = fmaxf(mx, __shfl_xor(mx, 16));
      mx = fmaxf(mx, __shfl_xor(mx, 32));
      float mn = fmaxf(m, mx);
      float corr = __expf(m - mn);
      m = mn;
      float ps = 0.f;
      #pragma unroll
      for (int i = 0; i < 8; ++i) { p[i] = __expf(p[i] - mn); ps += p[i]; }
      ps += __shfl_xor(ps, 16);
      ps += __shfl_xor(ps, 32);
      lsum = lsum * corr + ps;
      // P^T -> LDS at [q-local][k-local] (wave-private slice)
      #pragma unroll
      for (int r = 0; r < 4; ++r) {
        P_lds[w][lr][lh * 4 + r]      = (f16)p[r];
        P_lds[w][lr][16 + lh * 4 + r] = (f16)p[4 + r];
      }
      // broadcast corr to PV layout (q = q0 + lh*4 + r lives in lane lh*4+r)
      float corr4[4];
      #pragma unroll
      for (int r = 0; r < 4; ++r) corr4[r] = __shfl(corr, lh * 4 + r);
      #pragma unroll
      for (int dg = 0; dg < 4; ++dg)
        #pragma unroll
        for (int r = 0; r < 4; ++r) o[dg][r] *= corr4[r];
      f16x8 pf = *(const f16x8*)&P_lds[w][lr][lh * 8];   // A-frag: row=q, k contiguous
      #pragma unroll
      for (int dg = 0; dg < 4; ++dg) {
        f16x8 vf = *(const f16x8*)&Vb[(size_t)(dg * 16 + lr) * TT + kb + lh * 8];
        o[dg] = MFMA16(pf, vf, o[dg]);
      }
    }

    float linv = 1.0f / lsum;
    float linv4[4];
    #pragma unroll
    for (int r = 0; r < 4; ++r) linv4[r] = __shfl(linv, lh * 4 + r);
    #pragma unroll
    for (int dg = 0; dg < 4; ++dg)
      #pragma unroll
      for (int r = 0; r < 4; ++r) {
        int qq = q0 + lh * 4 + r;
        aout[((size_t)(b * TT + qq)) * CC + h * HS + dg * 16 + lr] =
            (f16)(o[dg][r] * linv4[r]);
      }
  }
}

// ---------------- launch ----------------
extern "C" void kernel_launch(void* const* d_in, const int* in_sizes, int n_in,
                              void* d_out, int out_size, void* d_ws, size_t ws_size,
                              hipStream_t stream) {
  const float* x      = (const float*)d_in[0];
  const float* w_kqv  = (const float*)d_in[1];
  const float* w_proj = (const float*)d_in[2];
  const float* b_proj = (const float*)d_in[3];
  float* out = (float*)d_out;

  char* ws = (char*)d_ws;
  f16* xb    = (f16*)(ws);                       // 16,777,216 B
  f16* wkqvT = (f16*)(ws + 16777216);            //  6,291,456
  f16* wpT   = (f16*)(ws + 23068672);            //  2,097,152
  f16* qT    = (f16*)(ws + 25165824);            // 16,777,216
  f16* kT    = (f16*)(ws + 41943040);            // 16,777,216
  f16* vT    = (f16*)(ws + 58720256);            // 16,777,216
  f16* aout  = (f16*)(ws + 75497472);            // 16,777,216  -> ~92.3 MB

  cvt_kernel<<<8192, 256, 0, stream>>>(x, xb, (MM * CC) / 4);
  transpose_cvt<<<dim3(3 * CC / 32, CC / 32), dim3(32, 8), 0, stream>>>(w_kqv, wkqvT, CC, 3 * CC);
  transpose_cvt<<<dim3(CC / 32, CC / 32), dim3(32, 8), 0, stream>>>(w_proj, wpT, CC, CC);

  gemm_bt<0><<<dim3(3 * CC / 128, MM / 128), 256, 0, stream>>>(xb, wkqvT, qT, kT, vT, nullptr, nullptr);

  attn_kernel<<<dim3(BB * HH, 16), 256, 0, stream>>>(qT, kT, vT, aout);

  gemm_bt<1><<<dim3(CC / 128, MM / 128), 256, 0, stream>>>(aout, wpT, nullptr, nullptr, nullptr, b_proj, out);
}